// Round 19
// baseline (143.419 us; speedup 1.0000x reference)
//
#include <hip/hip_runtime.h>
#include <stdint.h>

// pairs_of_pairs: fused [concat -> conv1x1+relu x3]
// B=32, C=64, S=64, CC=128, OC=256. 2016 rows of 64 positions.
// R18 = R17 + SQUARE wave tiles: 8 waves = 4 o-groups x 2 row-groups, wave =
// 64o x 64pos (was 32o x 128pos). LDS B-read traffic per block-layer halves
// (512KB -> 256KB: B per wave = pos_width*256k*2B); L2 A-traffic unchanged
// (4 distinct o-slices x 32KB x 3 layers = 384KB/block, row-group pair reads
// identical A lines -> L1-absorbed); loads/MFMA 0.625 -> 0.5. This is R7's
// tile shape minus R7's confounds (4 waves, 1 row, no overlap).
// Kept from R17: 2 rows/block (b0,b0+16), grid 1008, 512 thr, direct build
// with x-chunk reg-overlap into layer-0 kk0-3, X = 64KB 4-chunk swizzled
// (rolled chunk aliased from chunk2 at shifted pos), full kk unroll, direct
// 64B-segment stores with ZERO post-layer-2 barriers, launch_bounds(512,1).

typedef __attribute__((ext_vector_type(8))) __bf16 bf16x8;
typedef __attribute__((ext_vector_type(4))) float f32x4;
typedef __attribute__((ext_vector_type(4))) unsigned short u16x4;
typedef __attribute__((ext_vector_type(8))) unsigned short u16x8;

__device__ __forceinline__ unsigned short f2bf(float f) {
  unsigned int u = __builtin_bit_cast(unsigned int, f);
  u += 0x7FFFu + ((u >> 16) & 1u);
  return (unsigned short)(u >> 16);
}

// X: 4 chunk regions of [128 pos][64 ch] bf16 (8192 elems each).
// Within chunk: 16B-slot = pos*8 + ((c6/8) ^ (pos&7)) -> max 2-way (free).
__device__ __forceinline__ int xaddr(int pos, int c) {
  int slot = (pos << 3) + ((((c & 63) >> 3) ^ pos) & 7);
  return ((c >> 6) << 13) + (slot << 3) + (c & 7);
}

__global__ void wconv_kernel(const float* __restrict__ W1, const float* __restrict__ W2,
                             const float* __restrict__ W3, unsigned short* __restrict__ wb) {
  int i = (blockIdx.x * 256 + threadIdx.x) * 4;  // grid 64 -> 65536 per layer
  const float* Ws[3] = {W1, W2, W3};
#pragma unroll
  for (int L = 0; L < 3; ++L) {
    f32x4 a = *(const f32x4*)(Ws[L] + i);
    u16x4 p;
#pragma unroll
    for (int v = 0; v < 4; ++v) p[v] = f2bf(a[v]);
    *(u16x4*)(wb + L * 65536 + i) = p;
  }
}

__global__ __launch_bounds__(512, 1)
void fused_kernel(const float* __restrict__ x, const float* __restrict__ xc,
                  const unsigned short* __restrict__ wb,
                  const float* __restrict__ b1, const float* __restrict__ b2,
                  const float* __restrict__ b3, float* __restrict__ out) {
  __shared__ __align__(16) unsigned char lraw[65536];
  unsigned short* X = (unsigned short*)lraw;   // 64KB, 4 chunk regions

  const int r = blockIdx.x;       // 0..1007
  const int b0 = r / 63;          // 0..15 ; row1 uses b0+16
  const int dd = r % 63;
  const int d = dd + 1;
  const int tid = threadIdx.x;    // 0..511
  const int lane = tid & 63;
  const int g16 = lane >> 4;
  const int l16 = lane & 15;
  const int wv = tid >> 6;        // wave 0..7
  const int og = wv & 3;          // o-group: o in [og*64, og*64+64)
  const int rg = wv >> 2;         // row-group: pos in [rg*64, rg*64+64)
  const int ow = og * 64;
  const int pb = rg * 64;

  const int p = tid & 63;         // build: position owned by this thread
  const int c0 = (tid >> 6) << 3; // build: c-octet 0,8,...,56

  // ---- issue x-chunk loads FIRST (latency hidden under build + kk0-3) ----
  float xreg[2][8];
#pragma unroll
  for (int rr = 0; rr < 2; ++rr)
#pragma unroll
    for (int j = 0; j < 8; ++j)
      xreg[rr][j] = x[((b0 + 16 * rr) * 64 + c0 + j) * 64 + p];

  // ---- build chunks 0,1 (xc) for both rows: direct global->LDS ----
#pragma unroll
  for (int cr = 0; cr < 4; ++cr) {
    const int rr = cr >> 1;
    const int ck = cr & 1;
    const int b = b0 + 16 * rr;
    u16x8 v;
#pragma unroll
    for (int j = 0; j < 8; ++j)
      v[j] = f2bf(xc[(((b * 128 + ck * 64 + c0 + j) * 63) + dd) * 64 + p]);
    *(u16x8*)&X[xaddr(rr * 64 + p, ck * 64 + c0)] = v;
  }
  __syncthreads();  // chunks 0,1 ready

  // ---------------- 3 fused conv1x1+relu layers ----------------
  for (int layer = 0; layer < 3; ++layer) {
    const unsigned short* wl = wb + layer * 65536;
    const float* bias = (layer == 0) ? b1 : (layer == 1) ? b2 : b3;
    const bool al3 = (layer == 0);     // layer 0: k in [192,256) aliases chunk2 shifted

    f32x4 acc[4][4] = {};              // [mf][nf], wave tile = 64 o x 64 pos

#pragma unroll
    for (int kk = 0; kk < 8; ++kk) {   // FULL unroll; branches fold
      if (al3 && kk == 4) {
        // write x-chunk (c2) from regs, then barrier; kk0-3 used chunks 0,1 only
#pragma unroll
        for (int rr = 0; rr < 2; ++rr) {
          u16x8 v;
#pragma unroll
          for (int j = 0; j < 8; ++j) v[j] = f2bf(xreg[rr][j]);
          *(u16x8*)&X[xaddr(rr * 64 + p, 128 + c0)] = v;
        }
        __syncthreads();               // c2 ready for kk 4-7
      }
      int kb = kk * 32 + g16 * 8;      // this lane-group's k-base
      bool a3 = al3 && (kk >= 6);
      int cc = a3 ? (128 + (kb & 63)) : kb;  // rolled -> chunk2 region
      bf16x8 afr[4];
#pragma unroll
      for (int mf = 0; mf < 4; ++mf)
        afr[mf] = __builtin_bit_cast(
            bf16x8, *(const u16x8*)(wl + (ow + mf * 16 + l16) * 256 + kb));
      bf16x8 bfr[4];
#pragma unroll
      for (int nf = 0; nf < 4; ++nf) { // this row-group's 64 positions
        int i = nf * 16 + l16;         // 0..63 within row
        int ie = pb + (a3 ? ((i - d) & 63) : i);
        bfr[nf] = __builtin_bit_cast(bf16x8, *(const u16x8*)&X[xaddr(ie, cc)]);
      }
#pragma unroll
      for (int mf = 0; mf < 4; ++mf)
#pragma unroll
        for (int nf = 0; nf < 4; ++nf)
          acc[mf][nf] = __builtin_amdgcn_mfma_f32_16x16x32_bf16(afr[mf], bfr[nf], acc[mf][nf], 0, 0, 0);
    }

    if (layer < 2) {
      __syncthreads();  // all waves done reading X before it is overwritten
      // bias + relu -> bf16 back into X (D frag: pos = l16 col, o = g16*4+v)
#pragma unroll
      for (int mf = 0; mf < 4; ++mf) {
        int o0 = ow + mf * 16 + g16 * 4;
        f32x4 bv = *(const f32x4*)(bias + o0);
#pragma unroll
        for (int nf = 0; nf < 4; ++nf) {
          int pos = pb + nf * 16 + l16;
          u16x4 pk;
#pragma unroll
          for (int v = 0; v < 4; ++v)
            pk[v] = f2bf(fmaxf(acc[mf][nf][v] + bv[v], 0.f));
          *(u16x4*)&X[xaddr(pos, o0)] = pk;
        }
      }
      __syncthreads();
    } else {
      // layer 2: bias+relu -> DIRECT global stores, zero barriers.
      // For each (mf,nf,v): 16 lanes (l16) write 16 consecutive pos at fixed
      // o -> 64B segments (R14/R17-validated). Stores drain under the next
      // block's build on this CU.
      const int bq = b0 + 16 * rg;     // this wave's row
#pragma unroll
      for (int mf = 0; mf < 4; ++mf) {
        int o0 = ow + mf * 16 + g16 * 4;
        f32x4 bv = *(const f32x4*)(bias + o0);
#pragma unroll
        for (int nf = 0; nf < 4; ++nf) {
          int pos = nf * 16 + l16;     // within-row position
#pragma unroll
          for (int v = 0; v < 4; ++v)
            out[(((bq * 256 + o0 + v) * 63) + dd) * 64 + pos] =
                fmaxf(acc[mf][nf][v] + bv[v], 0.f);
        }
      }
    }
  }
}

extern "C" void kernel_launch(void* const* d_in, const int* in_sizes, int n_in,
                              void* d_out, int out_size, void* d_ws, size_t ws_size,
                              hipStream_t stream) {
  const float* x  = (const float*)d_in[0];
  const float* xc = (const float*)d_in[1];
  const float* W1 = (const float*)d_in[2];
  const float* b1 = (const float*)d_in[3];
  const float* W2 = (const float*)d_in[4];
  const float* b2 = (const float*)d_in[5];
  const float* W3 = (const float*)d_in[6];
  const float* b3 = (const float*)d_in[7];
  float* out = (float*)d_out;
  unsigned short* wb = (unsigned short*)d_ws;  // 3 x 256 x 256 bf16 = 384 KB

  wconv_kernel<<<64, 256, 0, stream>>>(W1, W2, W3, wb);
  fused_kernel<<<1008, 512, 0, stream>>>(x, xc, wb, b1, b2, b3, out);
}